// Round 1
// baseline (206.349 us; speedup 1.0000x reference)
//
#include <hip/hip_runtime.h>
#include <math.h>

#define B_N 131072
#define NSTRIPE 16
#define ST_STRIDE 4160          // 64 colsums + 4096 gram
// ---------------- ws layout (float offsets) ----------------
#define WS_STAT 0
#define ST_SZ   (NSTRIPE * ST_STRIDE)        // 66560
#define WS_MT2  66560                        // Mt2[64][20] (BN2 folded)
#define WS_C2   67840                        // C2[20]
#define WS_NH   67860                        // nhu[200], nhl[200]
#define WS_FT   68260                        // fast-act table 8*12 + flag = 97

__device__ __forceinline__ float gelu_exact(float v) {
    return 0.5f * v * (1.0f + erff(v * 0.70710678118654752440f));
}

// ---------------- pass 1: act + column sums + 64x64 Gram ----------------
// Each block: 8 chunks of 32 rows. act computed per (group,row) thread,
// staged to LDS (fp32), Gram accumulated as 4x4 subtile per thread over
// all 256 rows, one atomic flush per block at the end.
__global__ __launch_bounds__(256, 2) void k_stats(
    const float* __restrict__ x, const float* __restrict__ cen,
    const float* __restrict__ lw, const float* __restrict__ rw,
    const float* __restrict__ linw, float* __restrict__ stat)
{
    __shared__ float sAct[2][32][64];
    __shared__ float sAcc[4][8][8];
    const int t  = threadIdx.x;
    const int g  = t & 7;          // group for act compute
    const int rl = t >> 3;         // row-in-chunk 0..31
    const int gi = t >> 4;         // gram row subtile 0..15
    const int gj = t & 15;         // gram col subtile 0..15

    float c_[8], nh_[8], w_[8];
#pragma unroll
    for (int k = 0; k < 8; ++k) {
        c_[k] = cen[g * 8 + k];
        float s = expf(lw[g * 8 + k]) + 1e-6f;
        nh_[k] = -0.5f / (s * s);
        w_[k] = rw[g * 8 + k];
    }
    const float lin = linw[g];
    const float c0 = c_[0], nh0 = nh_[0];
    const float delta = c_[1] - c_[0];

    bool uni = true;
#pragma unroll
    for (int k = 0; k < 8; ++k) {
        float ck = c0 + (float)k * delta;
        uni = uni && (fabsf(c_[k] - ck) <= 1e-5f * (1.0f + fabsf(ck)));
        uni = uni && (fabsf(nh_[k] - nh0) <= 1e-6f * fabsf(nh0));
    }
    const bool fast = (bool)__all((int)uni);

    float W_[8];
    float k1c = 0.0f;
    if (fast) {
        k1c = -2.0f * delta * nh0;
#pragma unroll
        for (int k = 0; k < 8; ++k) {
            float kd = (float)k * delta;
            W_[k] = w_[k] * __expf(nh0 * kd * kd);
        }
    }

    float sumA[8];
#pragma unroll
    for (int f = 0; f < 8; ++f) sumA[f] = 0.0f;
    float Ga[4][4];
#pragma unroll
    for (int a = 0; a < 4; ++a)
#pragma unroll
        for (int b = 0; b < 4; ++b) Ga[a][b] = 0.0f;

    // prefetch chunk 0
    float4 pv0, pv1;
    {
        const float* xr = x + ((size_t)(blockIdx.x * 32 + rl)) * 64 + g * 8;
        pv0 = *(const float4*)xr;
        pv1 = *(const float4*)(xr + 4);
    }

    int p = 0;
#pragma unroll 1
    for (int c = 0; c < 8; ++c) {
        float xv[8] = {pv0.x, pv0.y, pv0.z, pv0.w, pv1.x, pv1.y, pv1.z, pv1.w};
        // issue next chunk's loads early (hide HBM latency under act+gram)
        if (c < 7) {
            const float* xr =
                x + ((size_t)(blockIdx.x * 32 + (c + 1) * 16384 + rl)) * 64 + g * 8;
            pv0 = *(const float4*)xr;
            pv1 = *(const float4*)(xr + 4);
        }
        float act[8];
        if (fast) {
#pragma unroll
            for (int f = 0; f < 8; ++f) {
                float v = xv[f];
                float dv = v - c0;
                float E0 = __expf(nh0 * dv * dv);
                float T  = __expf(k1c * dv);
                float poly = W_[7];
#pragma unroll
                for (int k = 6; k >= 0; --k) poly = poly * T + W_[k];
                act[f] = lin * v + E0 * poly;
            }
        } else {
#pragma unroll
            for (int f = 0; f < 8; ++f) {
                float v = xv[f];
                float a = lin * v;
#pragma unroll
                for (int k = 0; k < 8; ++k) {
                    float d = v - c_[k];
                    a += w_[k] * __expf(d * d * nh_[k]);
                }
                act[f] = a;
            }
        }
#pragma unroll
        for (int f = 0; f < 8; ++f) sumA[f] += act[f];
        *(float4*)&sAct[p][rl][g * 8]     = make_float4(act[0], act[1], act[2], act[3]);
        *(float4*)&sAct[p][rl][g * 8 + 4] = make_float4(act[4], act[5], act[6], act[7]);
        __syncthreads();
        const float (*buf)[64] = sAct[p];
#pragma unroll
        for (int r = 0; r < 32; ++r) {
            const float4 va = *(const float4*)&buf[r][gi * 4];
            const float4 vb = *(const float4*)&buf[r][gj * 4];
            Ga[0][0] += va.x * vb.x; Ga[0][1] += va.x * vb.y;
            Ga[0][2] += va.x * vb.z; Ga[0][3] += va.x * vb.w;
            Ga[1][0] += va.y * vb.x; Ga[1][1] += va.y * vb.y;
            Ga[1][2] += va.y * vb.z; Ga[1][3] += va.y * vb.w;
            Ga[2][0] += va.z * vb.x; Ga[2][1] += va.z * vb.y;
            Ga[2][2] += va.z * vb.z; Ga[2][3] += va.z * vb.w;
            Ga[3][0] += va.w * vb.x; Ga[3][1] += va.w * vb.y;
            Ga[3][2] += va.w * vb.z; Ga[3][3] += va.w * vb.w;
        }
        p ^= 1;
    }

    // column-sum reduce: lanes rl fold into lane<8 (lane==g)
#pragma unroll
    for (int off = 32; off >= 8; off >>= 1)
#pragma unroll
        for (int f = 0; f < 8; ++f) sumA[f] += __shfl_down(sumA[f], off, 64);
    const int wave = t >> 6, lane = t & 63;
    if (lane < 8) {
#pragma unroll
        for (int f = 0; f < 8; ++f) sAcc[wave][lane][f] = sumA[f];
    }
    __syncthreads();
    const int stripe = (blockIdx.x & (NSTRIPE - 1)) * ST_STRIDE;
    if (t < 64) {
        int gg = t >> 3, f = t & 7;
        float s = sAcc[0][gg][f] + sAcc[1][gg][f] + sAcc[2][gg][f] + sAcc[3][gg][f];
        atomicAdd(&stat[stripe + t], s);
    }
#pragma unroll
    for (int a = 0; a < 4; ++a)
#pragma unroll
        for (int b = 0; b < 4; ++b)
            atomicAdd(&stat[stripe + 64 + (gi * 4 + a) * 64 + (gj * 4 + b)], Ga[a][b]);
}

// ---------------- build: BN1 fold -> Mt/C, analytic BN2 fold -> Mt2/C2 ----------------
__global__ __launch_bounds__(256) void k_build(
    const float* __restrict__ stat, const float* __restrict__ Wp,
    const float* __restrict__ pb, const float* __restrict__ g1,
    const float* __restrict__ b1, const float* __restrict__ fpW,
    const float* __restrict__ fpb, const float* __restrict__ g2,
    const float* __restrict__ b2, const float* __restrict__ lsu,
    const float* __restrict__ lsl, const float* __restrict__ cen,
    const float* __restrict__ lw, const float* __restrict__ rw,
    const float* __restrict__ linw,
    float* __restrict__ Mt2, float* __restrict__ C2,
    float* __restrict__ nh, float* __restrict__ ftab)
{
    __shared__ float sG[4096];      // Sum over rows of a*a^T (unscaled)
    __shared__ float sAm[64];       // column means
    __shared__ float sa[128], sbb[128];
    __shared__ float sMt[1280];
    __shared__ float sC[20];
    __shared__ float sQ[20][8];
    __shared__ float sDM[20];
    __shared__ float sSc[20];
    __shared__ int   sUni[8];
    const int t = threadIdx.x;
    const float invB = 1.0f / (float)B_N;

    for (int i = t; i < ST_STRIDE; i += 256) {
        float s = 0.0f;
        for (int st = 0; st < NSTRIPE; ++st) s += stat[st * ST_STRIDE + i];
        if (i < 64) sAm[i] = s * invB;
        else        sG[i - 64] = s;
    }
    __syncthreads();

    // BN1 fold per channel
    if (t < 128) {
        const int g = t >> 4;
        float wv[8];
#pragma unroll
        for (int f = 0; f < 8; ++f) wv[f] = Wp[t * 8 + f];
        float dot = 0.0f;
#pragma unroll
        for (int f = 0; f < 8; ++f) dot += wv[f] * sAm[g * 8 + f];
        const float pbv = pb[t];
        const float mu = pbv + dot;
        float q = 0.0f;
#pragma unroll
        for (int f = 0; f < 8; ++f) {
            float inner = 0.0f;
#pragma unroll
            for (int f2 = 0; f2 < 8; ++f2)
                inner += wv[f2] * sG[(g * 8 + f) * 64 + (g * 8 + f2)];
            q += wv[f] * inner;
        }
        float e2 = pbv * pbv + 2.0f * pbv * dot + q * invB;
        float var = fmaxf(e2 - mu * mu, 0.0f);
        float a = g1[t] * rsqrtf(var + 1e-5f);
        sa[t] = a;
        sbb[t] = b1[t] - mu * a;
    }
    __syncthreads();

    // Mt (BN1 folded) and C
    for (int i = t; i < 1280; i += 256) {
        int gf = i / 20, j = i % 20;
        int g = gf >> 3, f = gf & 7;
        float m = 0.0f;
        for (int o = 0; o < 16; ++o) {
            int c = g * 16 + o;
            m += fpW[j * 128 + c] * sa[c] * Wp[c * 8 + f];
        }
        sMt[i] = m;
    }
    if (t < 20) {
        float cj = fpb[t];
        for (int c = 0; c < 128; ++c)
            cj += fpW[t * 128 + c] * (sa[c] * pb[c] + sbb[c]);
        sC[t] = cj;
    }
    __syncthreads();

    // quadratic forms m_j^T G m_j (split over 8 partial c-ranges) + mean dot
    if (t < 160) {
        int j = t >> 3, pp = t & 7;
        float qp = 0.0f;
        for (int c = pp * 8; c < pp * 8 + 8; ++c) {
            float inner = 0.0f;
            for (int c2 = 0; c2 < 64; ++c2)
                inner += sG[c * 64 + c2] * sMt[c2 * 20 + j];
            qp += sMt[c * 20 + j] * inner;
        }
        sQ[j][pp] = qp;
    } else if (t < 180) {
        int j = t - 160;
        float dm = 0.0f;
        for (int c = 0; c < 64; ++c) dm += sMt[c * 20 + j] * sAm[c];
        sDM[j] = dm;
    }
    __syncthreads();

    // BN2 fold: z stats computed analytically (exact empirical moments)
    if (t < 20) {
        float q = 0.0f;
#pragma unroll
        for (int pp = 0; pp < 8; ++pp) q += sQ[t][pp];
        q *= invB;
        float Cj  = sC[t];
        float dm  = sDM[t];
        float mu2 = Cj + dm;
        float Ez2 = Cj * Cj + 2.0f * Cj * dm + q;
        float var = fmaxf(Ez2 - mu2 * mu2, 0.0f);
        float sc = g2[t] * rsqrtf(var + 1e-5f);
        sSc[t] = sc;
        C2[t] = Cj * sc + (b2[t] - mu2 * sc);
    }
    __syncthreads();
    for (int i = t; i < 1280; i += 256) Mt2[i] = sMt[i] * sSc[i % 20];

    // fuzzy tables
    for (int i = t; i < 200; i += 256) {
        float su = expf(lsu[i]) + 1e-6f;
        float sl = fminf(expf(lsl[i]) + 1e-6f, 0.9f * su);
        nh[i]       = -0.5f / (su * su);
        nh[200 + i] = -0.5f / (sl * sl);
    }

    // fast-act table for k_out
    if (t < 8) {
        int gg = t;
        float c0 = cen[gg * 8];
        float delta = cen[gg * 8 + 1] - c0;
        float s0 = expf(lw[gg * 8]) + 1e-6f;
        float nh0 = -0.5f / (s0 * s0);
        bool uni = true;
        float Wk[8];
#pragma unroll
        for (int k = 0; k < 8; ++k) {
            float ck = cen[gg * 8 + k];
            float cke = c0 + (float)k * delta;
            uni = uni && (fabsf(ck - cke) <= 1e-5f * (1.0f + fabsf(cke)));
            float sk = expf(lw[gg * 8 + k]) + 1e-6f;
            float nhk = -0.5f / (sk * sk);
            uni = uni && (fabsf(nhk - nh0) <= 1e-6f * fabsf(nh0));
            float kd = (float)k * delta;
            Wk[k] = rw[gg * 8 + k] * __expf(nh0 * kd * kd);
        }
        ftab[gg * 12 + 0] = c0;
        ftab[gg * 12 + 1] = -2.0f * delta * nh0;
        ftab[gg * 12 + 2] = nh0;
        ftab[gg * 12 + 3] = linw[gg];
#pragma unroll
        for (int k = 0; k < 8; ++k) ftab[gg * 12 + 4 + k] = Wk[k];
        sUni[gg] = uni ? 1 : 0;
    }
    __syncthreads();
    if (t == 0) {
        int f = 1;
        for (int gg = 0; gg < 8; ++gg) f &= sUni[gg];
        ftab[96] = (float)f;
    }
}

// ---------------- pass 2: recompute act -> z~ (BN2 folded) -> GELU -> fuzzy -> head ----------------
__global__ __launch_bounds__(256, 2) void k_out(
    const float* __restrict__ x, const float* __restrict__ cen,
    const float* __restrict__ lw, const float* __restrict__ rw,
    const float* __restrict__ linw, const float* __restrict__ Mt2,
    const float* __restrict__ C2, const float* __restrict__ nh,
    const float* __restrict__ fzc, const float* __restrict__ hW,
    const float* __restrict__ hb, const float* __restrict__ ftab,
    float* __restrict__ out)
{
    __shared__ __align__(16) float sMt[1280];
    __shared__ float sC[20];
    __shared__ float sTab[97];
    __shared__ __align__(16) float4 sRbf[64];
    __shared__ float sLin[8];
    const int t = threadIdx.x;
    for (int i = t; i < 1280; i += 256) sMt[i] = Mt2[i];
    if (t < 20) sC[t] = C2[t];
    if (t < 97) sTab[t] = ftab[t];
    if (t < 64) {
        float s = expf(lw[t]) + 1e-6f;
        sRbf[t] = make_float4(cen[t], rw[t], -0.5f / (s * s), 0.0f);
    }
    if (t < 8) sLin[t] = linw[t];
    __syncthreads();
    const bool fast = (sTab[96] > 0.5f);

    const int row = blockIdx.x * 256 + t;
    const float* xr = x + (size_t)row * 64;
    float zp[20];
#pragma unroll
    for (int j = 0; j < 20; ++j) zp[j] = sC[j];

#pragma unroll 1
    for (int g = 0; g < 8; ++g) {
        float4 v0 = *(const float4*)(xr + g * 8);
        float4 v1 = *(const float4*)(xr + g * 8 + 4);
        float xv[8] = {v0.x, v0.y, v0.z, v0.w, v1.x, v1.y, v1.z, v1.w};
        float act[8];
        if (fast) {
            const float c0  = sTab[g * 12 + 0];
            const float k1c = sTab[g * 12 + 1];
            const float nh0 = sTab[g * 12 + 2];
            const float lin = sTab[g * 12 + 3];
            float Wk[8];
#pragma unroll
            for (int k = 0; k < 8; ++k) Wk[k] = sTab[g * 12 + 4 + k];
#pragma unroll
            for (int f = 0; f < 8; ++f) {
                float v = xv[f];
                float dv = v - c0;
                float E0 = __expf(nh0 * dv * dv);
                float T  = __expf(k1c * dv);
                float poly = Wk[7];
#pragma unroll
                for (int k = 6; k >= 0; --k) poly = poly * T + Wk[k];
                act[f] = lin * v + E0 * poly;
            }
        } else {
            float lin = sLin[g];
#pragma unroll
            for (int f = 0; f < 8; ++f) act[f] = lin * xv[f];
#pragma unroll 1
            for (int k = 0; k < 8; ++k) {
                float4 pr = sRbf[g * 8 + k];
#pragma unroll
                for (int f = 0; f < 8; ++f) {
                    float d = xv[f] - pr.x;
                    act[f] += pr.y * __expf(d * d * pr.z);
                }
            }
        }
#pragma unroll 1
        for (int f = 0; f < 8; ++f) {
            float av = act[f];
            const float4* m4 = (const float4*)(sMt + (g * 8 + f) * 20);
            float4 ma = m4[0], mb = m4[1], mc = m4[2], md = m4[3], me = m4[4];
            zp[0] += av * ma.x; zp[1] += av * ma.y; zp[2] += av * ma.z; zp[3] += av * ma.w;
            zp[4] += av * mb.x; zp[5] += av * mb.y; zp[6] += av * mb.z; zp[7] += av * mb.w;
            zp[8] += av * mc.x; zp[9] += av * mc.y; zp[10] += av * mc.z; zp[11] += av * mc.w;
            zp[12] += av * md.x; zp[13] += av * md.y; zp[14] += av * md.z; zp[15] += av * md.w;
            zp[16] += av * me.x; zp[17] += av * me.y; zp[18] += av * me.z; zp[19] += av * me.w;
        }
    }

    // zp is already BN2-normalized (folded into Mt2/C2)
#pragma unroll
    for (int j = 0; j < 20; ++j) zp[j] = gelu_exact(zp[j]);

    float acc = hb[0];
#pragma unroll 1
    for (int r = 0; r < 10; ++r) {
        float u = 0.0f, l = 0.0f;
#pragma unroll
        for (int j = 0; j < 20; ++j) {
            float cx = fzc[r * 20 + j];
            float pu = nh[r * 20 + j];
            float pl = nh[200 + r * 20 + j];
            float d = zp[j] - cx;
            float dd = d * d;
            u += __expf(dd * pu);
            l += __expf(dd * pl);
        }
        acc += hW[r] * 0.025f * (u + l);
    }
    out[row] = acc;
}

// ---------------- launcher ----------------
extern "C" void kernel_launch(void* const* d_in, const int* in_sizes, int n_in,
                              void* d_out, int out_size, void* d_ws, size_t ws_size,
                              hipStream_t stream) {
    const float* x    = (const float*)d_in[0];
    const float* cen  = (const float*)d_in[1];
    const float* lw   = (const float*)d_in[2];
    const float* rw   = (const float*)d_in[3];
    const float* linw = (const float*)d_in[4];
    const float* Wp   = (const float*)d_in[5];
    const float* pb   = (const float*)d_in[6];
    const float* g1   = (const float*)d_in[7];
    const float* b1   = (const float*)d_in[8];
    const float* fpW  = (const float*)d_in[9];
    const float* fpb  = (const float*)d_in[10];
    const float* g2   = (const float*)d_in[11];
    const float* b2   = (const float*)d_in[12];
    const float* fzc  = (const float*)d_in[13];
    const float* lsu  = (const float*)d_in[14];
    const float* lsl  = (const float*)d_in[15];
    const float* hW   = (const float*)d_in[16];
    const float* hb   = (const float*)d_in[17];

    float* ws   = (float*)d_ws;
    float* stat = ws + WS_STAT;
    float* Mt2  = ws + WS_MT2;
    float* C2   = ws + WS_C2;
    float* nh   = ws + WS_NH;
    float* ftab = ws + WS_FT;
    float* outp = (float*)d_out;

    hipMemsetAsync(stat, 0, (size_t)ST_SZ * sizeof(float), stream);
    k_stats<<<512, 256, 0, stream>>>(x, cen, lw, rw, linw, stat);
    k_build<<<1, 256, 0, stream>>>(stat, Wp, pb, g1, b1, fpW, fpb, g2, b2,
                                   lsu, lsl, cen, lw, rw, linw,
                                   Mt2, C2, nh, ftab);
    k_out<<<512, 256, 0, stream>>>(x, cen, lw, rw, linw, Mt2, C2, nh, fzc,
                                   hW, hb, ftab, outp);
}